// Round 2
// baseline (1202.659 us; speedup 1.0000x reference)
//
#include <hip/hip_runtime.h>
#include <hip/hip_bf16.h>

#define T_TOK    4096
#define HDIM     1024
#define NEXP     8
#define FDIM     4096
#define TK_SLOTS 8192
#define BM       64
#define BN       64
#define BKK      32
#define LDK      (BKK + 8)
#define MAXTILES 136

typedef __attribute__((ext_vector_type(8))) short bf16x8;
typedef __attribute__((ext_vector_type(4))) float f32x4;

__device__ __forceinline__ short f2b(float f) {
    __hip_bfloat16 h = __float2bfloat16(f);
    return __builtin_bit_cast(short, h);
}

// ---------------- gating: one wave per token ----------------
__global__ __launch_bounds__(256) void gate_kernel(
    const float* __restrict__ x, const float* __restrict__ gw,
    int* __restrict__ idx, float* __restrict__ gates, int* __restrict__ counts)
{
    const int lane = threadIdx.x & 63;
    const int wid  = threadIdx.x >> 6;
    const int t = blockIdx.x * 4 + wid;
    const float* xt = x + (size_t)t * HDIM;

    float acc[NEXP];
#pragma unroll
    for (int e = 0; e < NEXP; ++e) acc[e] = 0.f;
    for (int i = lane; i < HDIM; i += 64) {
        const float xv = xt[i];
#pragma unroll
        for (int e = 0; e < NEXP; ++e) acc[e] += xv * gw[e * HDIM + i];
    }
#pragma unroll
    for (int off = 32; off > 0; off >>= 1) {
#pragma unroll
        for (int e = 0; e < NEXP; ++e) acc[e] += __shfl_xor(acc[e], off);
    }
    if (lane == 0) {
        float m = acc[0];
#pragma unroll
        for (int e = 1; e < NEXP; ++e) m = fmaxf(m, acc[e]);
        float p[NEXP]; float s = 0.f;
#pragma unroll
        for (int e = 0; e < NEXP; ++e) { p[e] = __expf(acc[e] - m); s += p[e]; }
        // top-2, first index wins ties (matches jax top_k)
        int i0 = 0; float v0 = p[0];
#pragma unroll
        for (int e = 1; e < NEXP; ++e) if (p[e] > v0) { v0 = p[e]; i0 = e; }
        int i1 = -1; float v1 = -1.f;
#pragma unroll
        for (int e = 0; e < NEXP; ++e) if (e != i0 && p[e] > v1) { v1 = p[e]; i1 = e; }
        v0 /= s; v1 /= s;
        const float den = v0 + v1 + 1e-8f;
        idx[t * 2 + 0] = i0; idx[t * 2 + 1] = i1;
        gates[t * 2 + 0] = v0 / den; gates[t * 2 + 1] = v1 / den;
        atomicAdd(&counts[i0], 1);
        atomicAdd(&counts[i1], 1);
    }
}

// ---------------- schedule: bases, tiles, load-balance loss ----------------
__global__ void schedule_kernel(const int* __restrict__ counts, int* __restrict__ base,
                                int* __restrict__ cursor, int* __restrict__ tile_desc,
                                float* __restrict__ loss_out)
{
    if (threadIdx.x != 0 || blockIdx.x != 0) return;
    int b = 0, nt = 0;
    for (int e = 0; e < NEXP; ++e) {
        base[e] = b; cursor[e] = 0;
        const int n = counts[e];
        for (int r = 0; r < n; r += BM) {
            tile_desc[nt * 3 + 0] = e;
            tile_desc[nt * 3 + 1] = b + r;                       // global slot start
            tile_desc[nt * 3 + 2] = (n - r < BM) ? (n - r) : BM; // rows in tile
            ++nt;
        }
        b += n;
    }
    for (int i = nt; i < MAXTILES; ++i) tile_desc[i * 3 + 0] = -1;

    float var = 0.f;
    for (int e = 0; e < NEXP; ++e) {
        const float u = (float)counts[e] / (float)TK_SLOTS;
        const float d = u - 0.125f;   // mean(usage) == 1/E exactly
        var += d * d;
    }
    var /= (float)(NEXP - 1);         // ddof = 1
    const float lb = var / (0.125f + 1e-8f);
    loss_out[0] = lb * lb;
}

// ---------------- scatter tokens into expert-grouped slots ----------------
__global__ __launch_bounds__(256) void scatter_kernel(
    const int* __restrict__ idx, const float* __restrict__ gates,
    const int* __restrict__ base, int* __restrict__ cursor,
    int* __restrict__ slot_token, float* __restrict__ slot_w)
{
    const int t = blockIdx.x * 256 + threadIdx.x;
#pragma unroll
    for (int k = 0; k < 2; ++k) {
        const int e = idx[t * 2 + k];
        const int pos = atomicAdd(&cursor[e], 1);
        const int slot = base[e] + pos;
        slot_token[slot] = t;
        slot_w[slot] = gates[t * 2 + k];
    }
}

// ---------------- pass 1: g = X Wg^T, u = X Wu^T, h = g * silu(u) ----------------
__global__ __launch_bounds__(256) void gemm1_kernel(
    const float* __restrict__ x, const float* __restrict__ Wg, const float* __restrict__ Wu,
    const int* __restrict__ slot_token, const int* __restrict__ tile_desc,
    __hip_bfloat16* __restrict__ hbuf)
{
    const int e = tile_desc[blockIdx.x * 3 + 0];
    if (e < 0) return;
    const int slot0 = tile_desc[blockIdx.x * 3 + 1];
    const int nrows = tile_desc[blockIdx.x * 3 + 2];
    const int ncol0 = blockIdx.y * BN;
    const float* __restrict__ wg = Wg + (size_t)e * FDIM * HDIM;
    const float* __restrict__ wu = Wu + (size_t)e * FDIM * HDIM;

    __shared__ short As[BM][LDK];
    __shared__ short Bgs[BN][LDK];
    __shared__ short Bus[BN][LDK];

    const int tid  = threadIdx.x;
    const int lane = tid & 63;
    const int wid  = tid >> 6;
    const int wr   = wid >> 1, wc = wid & 1;

    const int srow = tid >> 2;          // 0..63
    const int skc  = (tid & 3) * 8;     // 0,8,16,24
    int tok = -1;
    if (srow < nrows) tok = slot_token[slot0 + srow];

    f32x4 accg[2][2] = {};
    f32x4 accu[2][2] = {};

    for (int k0 = 0; k0 < HDIM; k0 += BKK) {
        __syncthreads();
        // stage A (gathered token rows, fp32 -> bf16)
        {
            bf16x8 t8;
            if (tok >= 0) {
                const float4* p = reinterpret_cast<const float4*>(x + (size_t)tok * HDIM + k0 + skc);
                const float4 a = p[0], b = p[1];
                t8[0] = f2b(a.x); t8[1] = f2b(a.y); t8[2] = f2b(a.z); t8[3] = f2b(a.w);
                t8[4] = f2b(b.x); t8[5] = f2b(b.y); t8[6] = f2b(b.z); t8[7] = f2b(b.w);
            } else {
#pragma unroll
                for (int j = 0; j < 8; ++j) t8[j] = 0;
            }
            *reinterpret_cast<bf16x8*>(&As[srow][skc]) = t8;
        }
        // stage Bg, Bu (weight rows = output f columns, fp32 -> bf16)
        {
            const float4* pg = reinterpret_cast<const float4*>(wg + (size_t)(ncol0 + srow) * HDIM + k0 + skc);
            float4 a = pg[0], b = pg[1];
            bf16x8 t8;
            t8[0] = f2b(a.x); t8[1] = f2b(a.y); t8[2] = f2b(a.z); t8[3] = f2b(a.w);
            t8[4] = f2b(b.x); t8[5] = f2b(b.y); t8[6] = f2b(b.z); t8[7] = f2b(b.w);
            *reinterpret_cast<bf16x8*>(&Bgs[srow][skc]) = t8;
            const float4* pu = reinterpret_cast<const float4*>(wu + (size_t)(ncol0 + srow) * HDIM + k0 + skc);
            a = pu[0]; b = pu[1];
            t8[0] = f2b(a.x); t8[1] = f2b(a.y); t8[2] = f2b(a.z); t8[3] = f2b(a.w);
            t8[4] = f2b(b.x); t8[5] = f2b(b.y); t8[6] = f2b(b.z); t8[7] = f2b(b.w);
            *reinterpret_cast<bf16x8*>(&Bus[srow][skc]) = t8;
        }
        __syncthreads();

        bf16x8 af[2], bgf[2], buf_[2];
#pragma unroll
        for (int m = 0; m < 2; ++m)
            af[m] = *reinterpret_cast<const bf16x8*>(&As[wr * 32 + m * 16 + (lane & 15)][(lane >> 4) * 8]);
#pragma unroll
        for (int n = 0; n < 2; ++n) {
            bgf[n]  = *reinterpret_cast<const bf16x8*>(&Bgs[wc * 32 + n * 16 + (lane & 15)][(lane >> 4) * 8]);
            buf_[n] = *reinterpret_cast<const bf16x8*>(&Bus[wc * 32 + n * 16 + (lane & 15)][(lane >> 4) * 8]);
        }
#pragma unroll
        for (int m = 0; m < 2; ++m)
#pragma unroll
            for (int n = 0; n < 2; ++n) {
                accg[m][n] = __builtin_amdgcn_mfma_f32_16x16x32_bf16(af[m], bgf[n], accg[m][n], 0, 0, 0);
                accu[m][n] = __builtin_amdgcn_mfma_f32_16x16x32_bf16(af[m], buf_[n], accu[m][n], 0, 0, 0);
            }
    }

    // epilogue: h = g * silu(u) -> bf16
#pragma unroll
    for (int m = 0; m < 2; ++m)
#pragma unroll
        for (int n = 0; n < 2; ++n)
#pragma unroll
            for (int r = 0; r < 4; ++r) {
                const int row = wr * 32 + m * 16 + ((lane >> 4) << 2) + r;
                const int col = ncol0 + wc * 32 + n * 16 + (lane & 15);
                if (row < nrows) {
                    const float g = accg[m][n][r];
                    const float u = accu[m][n][r];
                    const float hv = g * (u / (1.0f + __expf(-u)));
                    hbuf[(size_t)(slot0 + row) * FDIM + col] = __float2bfloat16(hv);
                }
            }
}

// ---------------- pass 2: out[t] += w * (h @ Wd^T) ----------------
__global__ __launch_bounds__(256) void gemm2_kernel(
    const __hip_bfloat16* __restrict__ hbuf, const float* __restrict__ Wd,
    const int* __restrict__ slot_token, const float* __restrict__ slot_w,
    const int* __restrict__ tile_desc, float* __restrict__ out)
{
    const int e = tile_desc[blockIdx.x * 3 + 0];
    if (e < 0) return;
    const int slot0 = tile_desc[blockIdx.x * 3 + 1];
    const int nrows = tile_desc[blockIdx.x * 3 + 2];
    const int ncol0 = blockIdx.y * BN;
    const float* __restrict__ wd = Wd + (size_t)e * HDIM * FDIM;

    __shared__ short As[BM][LDK];
    __shared__ short Bs[BN][LDK];

    const int tid  = threadIdx.x;
    const int lane = tid & 63;
    const int wid  = tid >> 6;
    const int wr   = wid >> 1, wc = wid & 1;

    const int srow = tid >> 2;
    const int skc  = (tid & 3) * 8;

    f32x4 acc[2][2] = {};

    for (int k0 = 0; k0 < FDIM; k0 += BKK) {
        __syncthreads();
        // stage A: already bf16
        {
            int4 av = make_int4(0, 0, 0, 0);
            if (srow < nrows)
                av = *reinterpret_cast<const int4*>(hbuf + (size_t)(slot0 + srow) * FDIM + k0 + skc);
            *reinterpret_cast<int4*>(&As[srow][skc]) = av;
        }
        // stage B: Wd rows (output h columns), fp32 -> bf16
        {
            const float4* p = reinterpret_cast<const float4*>(wd + (size_t)(ncol0 + srow) * FDIM + k0 + skc);
            const float4 a = p[0], b = p[1];
            bf16x8 t8;
            t8[0] = f2b(a.x); t8[1] = f2b(a.y); t8[2] = f2b(a.z); t8[3] = f2b(a.w);
            t8[4] = f2b(b.x); t8[5] = f2b(b.y); t8[6] = f2b(b.z); t8[7] = f2b(b.w);
            *reinterpret_cast<bf16x8*>(&Bs[srow][skc]) = t8;
        }
        __syncthreads();

        bf16x8 af[2], bf[2];
#pragma unroll
        for (int m = 0; m < 2; ++m)
            af[m] = *reinterpret_cast<const bf16x8*>(&As[wr * 32 + m * 16 + (lane & 15)][(lane >> 4) * 8]);
#pragma unroll
        for (int n = 0; n < 2; ++n)
            bf[n] = *reinterpret_cast<const bf16x8*>(&Bs[wc * 32 + n * 16 + (lane & 15)][(lane >> 4) * 8]);
#pragma unroll
        for (int m = 0; m < 2; ++m)
#pragma unroll
            for (int n = 0; n < 2; ++n)
                acc[m][n] = __builtin_amdgcn_mfma_f32_16x16x32_bf16(af[m], bf[n], acc[m][n], 0, 0, 0);
    }

#pragma unroll
    for (int m = 0; m < 2; ++m)
#pragma unroll
        for (int n = 0; n < 2; ++n)
#pragma unroll
            for (int r = 0; r < 4; ++r) {
                const int row = wr * 32 + m * 16 + ((lane >> 4) << 2) + r;
                const int col = ncol0 + wc * 32 + n * 16 + (lane & 15);
                if (row < nrows) {
                    const int   t = slot_token[slot0 + row];
                    const float w = slot_w[slot0 + row];
                    atomicAdd(&out[(size_t)t * HDIM + col], w * acc[m][n][r]);
                }
            }
}

extern "C" void kernel_launch(void* const* d_in, const int* in_sizes, int n_in,
                              void* d_out, int out_size, void* d_ws, size_t ws_size,
                              hipStream_t stream) {
    const float* x  = (const float*)d_in[0];
    const float* gw = (const float*)d_in[1];
    const float* Wg = (const float*)d_in[2];
    const float* Wu = (const float*)d_in[3];
    const float* Wd = (const float*)d_in[4];
    float* out = (float*)d_out;

    char* ws = (char*)d_ws;
    __hip_bfloat16* hbuf = (__hip_bfloat16*)ws;
    size_t off = (size_t)TK_SLOTS * FDIM * 2;          // 64 MiB
    int*   slot_token = (int*)(ws + off);   off += TK_SLOTS * 4;
    float* slot_w     = (float*)(ws + off); off += TK_SLOTS * 4;
    int*   idx        = (int*)(ws + off);   off += T_TOK * 2 * 4;
    float* gates      = (float*)(ws + off); off += T_TOK * 2 * 4;
    int*   meta       = (int*)(ws + off);   off += 32 * 4;  // counts[8], base[8], cursor[8], pad
    int*   counts = meta;
    int*   base   = meta + 8;
    int*   cursor = meta + 16;
    int*   tile_desc  = (int*)(ws + off);   off += MAXTILES * 3 * 4;

    hipMemsetAsync(out, 0, (size_t)out_size * sizeof(float), stream);
    hipMemsetAsync(meta, 0, 32 * 4, stream);

    gate_kernel<<<T_TOK / 4, 256, 0, stream>>>(x, gw, idx, gates, counts);
    schedule_kernel<<<1, 64, 0, stream>>>(counts, base, cursor, tile_desc,
                                          out + (size_t)T_TOK * HDIM);
    scatter_kernel<<<T_TOK / 256, 256, 0, stream>>>(idx, gates, base, cursor,
                                                    slot_token, slot_w);
    dim3 g1(MAXTILES, FDIM / BN);
    gemm1_kernel<<<g1, 256, 0, stream>>>(x, Wg, Wu, slot_token, tile_desc, hbuf);
    dim3 g2(MAXTILES, HDIM / BN);
    gemm2_kernel<<<g2, 256, 0, stream>>>(hbuf, Wd, slot_token, slot_w, tile_desc, out);
}